// Round 17
// baseline (81.011 us; speedup 1.0000x reference)
//
#include <hip/hip_runtime.h>

// BandSplit R17: CHUNK 128 -> 64. WIN=288, K2=576 (18 phases, -23% MFMA and
// Mb L2 traffic vs CHUNK=128), OC=128 -> 8 waves x 1 ct at 512 threads,
// LDS 37.4KB -> 4 blocks x 8 waves = 32 waves/CU with small blocks.
// Setup chain unchanged from R16 (clean A/B on the banded kernel).

#define K_BANDS 64
#define COUT_D  128
#define T_DIM   1024
#define B_DIM   4
#define F_DIM   1025
#define WPAD    112      // padded band width (W <= 112, verified R2-R16)
#define DINP    224      // 2*WPAD, channel-blocked j/i = c*112 + wi
#define NMT     14       // DINP/16 tiles (compose geometry)
#define NKTC    4        // 128/32 compose-K tiles
#define CHUNK   64       // output f-bins per chunk
#define NCHUNK  17       // ceil(1025/64)
#define WIN     288      // 112 + 64 + 112 input window
#define K2      576      // 2*WIN
#define KT2     18       // K2/32
#define OC      128      // out cols per chunk (2ch x 64)
#define NCT     8        // OC/16
#define M_TILE  32       // rows per main block
#define SXLD    584      // s_x row stride (shorts): 292 dw %32=4 -> spread

typedef __attribute__((ext_vector_type(8))) short bf16x8;
typedef __attribute__((ext_vector_type(4))) float f32x4;

__device__ __forceinline__ unsigned short f2bf(float f) {
    unsigned u = __builtin_bit_cast(unsigned, f);
    u += 0x7FFFu + ((u >> 16) & 1u);          // RNE
    return (unsigned short)(u >> 16);
}
__device__ __forceinline__ void st8(unsigned short* o, const unsigned short* v) {
    *(ushort4*)(o)     = make_ushort4(v[0], v[1], v[2], v[3]);
    *(ushort4*)(o + 4) = make_ushort4(v[4], v[5], v[6], v[7]);
}

struct alignas(4) f4u { float v[4]; };        // dword-aligned 16B load

// ---- prep: zero Mf+bias slice, pack post' B-frags only
__global__ __launch_bounds__(256) void bs_prep(
    const float* __restrict__ post_w, const int* __restrict__ idx,
    const float* __restrict__ melw, const float* __restrict__ mask,
    const float* __restrict__ ola, unsigned short* __restrict__ dstB,
    float* __restrict__ zbase, int zcount, int W, int din)
{
    const int k = blockIdx.x, kt = blockIdx.y;
    {
        const int nblk = gridDim.x * gridDim.y;
        const int bid  = blockIdx.y * gridDim.x + blockIdx.x;
        const int nthr = nblk * 256;
        for (int i = bid * 256 + threadIdx.x; i < zcount; i += nthr)
            zbase[i] = 0.f;
    }
    for (int q = threadIdx.x; q < NMT * 64; q += 256) {
        const int ct = q >> 6, lane = q & 63;
        const int col = lane & 15, kg = lane >> 4;
        const int i  = ct * 16 + col;
        const int cc = (i >= WPAD);
        const int wi = i - cc * WPAD;
        float sc = 0.f;
        if (wi < W) {
            const float mw = melw[k * W + wi] * mask[k * W + wi];
            if (mw != 0.f) sc = 1.0f / ola[idx[k * W + wi]];
        }
        unsigned short v[8];
#pragma unroll
        for (int e = 0; e < 8; ++e) {
            const int o = kt * 32 + kg * 8 + e;
            const float f = (sc != 0.f)
                ? sc * post_w[((size_t)k * COUT_D + o) * din + 2 * wi + cc] : 0.f;
            v[e] = f2bf(f);
        }
        st8(dstB + ((((size_t)k * NKTC + kt) * NMT + ct) * 64 + lane) * 8, v);
    }
}

// ---- compose A_k = pre'^T x post', atomicAdd into banded Mf.
// A-frags built on the fly.  mt in [0,14): compose; mt == 14: bias.
__global__ __launch_bounds__(256) void bs_compose(
    const unsigned short* __restrict__ postP,
    const float* __restrict__ pre_w,  const float* __restrict__ pre_b,
    const float* __restrict__ post_w, const float* __restrict__ post_b,
    const int* __restrict__ idx, const float* __restrict__ melw,
    const float* __restrict__ mask, const float* __restrict__ ola,
    float* __restrict__ Mf, float* __restrict__ bias_g, int W, int din)
{
    __shared__ unsigned char s_flag[DINP];
    const int k   = blockIdx.x;
    const int mt  = blockIdx.y;
    const int tid = threadIdx.x;
    const int f0  = idx[(size_t)k * W];

    if (mt == NMT) {          // bias block
        if (tid >= DINP) return;
        const int c = tid >= WPAD, wi = tid - c * WPAD;
        if (wi >= W) return;
        if (melw[k * W + wi] * mask[k * W + wi] == 0.f) return;
        const int f = idx[k * W + wi];
        float v = post_b[(size_t)k * din + 2 * wi + c];
        for (int o = 0; o < COUT_D; ++o)
            v += pre_b[k * COUT_D + o]
                 * post_w[((size_t)k * COUT_D + o) * din + 2 * wi + c];
        atomicAdd(bias_g + c * F_DIM + f, v / ola[f]);
        return;
    }

    if (tid < DINP) {
        const int cc = tid >= WPAD, wi = tid - cc * WPAD;
        s_flag[tid] = (wi < W) && (melw[k * W + wi] * mask[k * W + wi] != 0.f);
    }
    __syncthreads();

    const int lane = tid & 63, wave = tid >> 6;
    const int col  = lane & 15, kg  = lane >> 4;
    const bf16x8* bp = (const bf16x8*)(postP + (size_t)k * NKTC * NMT * 512);

    // build A-frags in regs: j = mt*16+col, o = kt*32+kg*8+e, value wt(j)*pre_w
    bf16x8 a[NKTC];
    {
        const int jl  = mt * 16 + col;
        const int cc2 = jl >= WPAD, wj = jl - cc2 * WPAD;
        float wt = 0.f;
        if (wj < W) wt = melw[k * W + wj] * mask[k * W + wj];
#pragma unroll
        for (int kt = 0; kt < NKTC; ++kt) {
            bf16x8 av = (bf16x8){0, 0, 0, 0, 0, 0, 0, 0};
            if (wt != 0.f) {
                const float* src = pre_w
                    + ((size_t)k * din + 2 * wj + cc2) * COUT_D + kt * 32 + kg * 8;
                const f4u p0 = *(const f4u*)(src);
                const f4u p1 = *(const f4u*)(src + 4);
#pragma unroll
                for (int e = 0; e < 4; ++e) {
                    av[e]     = (short)f2bf(wt * p0.v[e]);
                    av[e + 4] = (short)f2bf(wt * p1.v[e]);
                }
            }
            a[kt] = av;
        }
    }

    for (int nt = wave; nt < NMT; nt += 4) {
        f32x4 acc = (f32x4){0.f, 0.f, 0.f, 0.f};
#pragma unroll
        for (int kt = 0; kt < NKTC; ++kt)
            acc = __builtin_amdgcn_mfma_f32_16x16x32_bf16(
                a[kt], bp[(kt * NMT + nt) * 64 + lane], acc, 0, 0, 0);
        const int i_loc = nt * 16 + col;
        if (!s_flag[i_loc]) continue;
        const int c  = i_loc >= WPAD, wi = i_loc - c * WPAD;
        const int f  = f0 + wi;                // output bin
        const int ch = f >> 6, df = f & 63;    // CHUNK = 64
        const int lo = (ch << 6) - WPAD;
        const size_t colIdx = (size_t)(c * CHUNK + df);
#pragma unroll
        for (int reg = 0; reg < 4; ++reg) {
            const int j_loc = mt * 16 + kg * 4 + reg;
            if (!s_flag[j_loc]) continue;
            const int c2 = j_loc >= WPAD, wi2 = j_loc - c2 * WPAD;
            const int jj = f0 + wi2 - lo;      // in [1, 286] subset of WIN
            atomicAdd(Mf + ((size_t)ch * K2 + c2 * WIN + jj) * OC + colIdx,
                      acc[reg]);
        }
    }
}

// ---- convert banded Mf32 -> bf16 B-frags: (chunk, kt, ct, lane, 8)
__global__ __launch_bounds__(256) void bs_mk_bf16(
    const float* __restrict__ Mf, unsigned short* __restrict__ Mb)
{
    const int chunk = blockIdx.x, kt = blockIdx.y;
    for (int q = threadIdx.x; q < NCT * 64; q += 256) {
        const int ct = q >> 6, lane = q & 63;
        const int col = lane & 15, kg = lane >> 4;
        unsigned short v[8];
#pragma unroll
        for (int e = 0; e < 8; ++e) {
            const int jp = kt * 32 + kg * 8 + e;
            v[e] = f2bf(Mf[((size_t)chunk * K2 + jp) * OC + ct * 16 + col]);
        }
        st8(Mb + ((((size_t)chunk * KT2 + kt) * NCT + ct) * 64 + lane) * 8, v);
    }
}

// ---- main: out_row = M . x_window + bias.  CHUNK=64: 512 threads / 8 waves,
// 1 ct per wave, 18 phases, 37.4KB LDS -> 4 blocks x 8 waves = 32 waves/CU.
__global__ __launch_bounds__(512) void bs_banded(
    const float* __restrict__ x, const unsigned short* __restrict__ Mb,
    const float* __restrict__ bias_g, float* __restrict__ out)
{
    __shared__ unsigned short s_x[M_TILE][SXLD];

    const int chunk  = blockIdx.y;                // t-tile fastest
    const int m_base = blockIdx.x * M_TILE;
    const int tid    = threadIdx.x;
    const int lo     = chunk * CHUNK - WPAD;      // may be negative / past end

    for (int p = tid; p < M_TILE * 2 * 72; p += 512) {
        const int seg = p / 72, q = p - seg * 72;
        const int row = seg >> 1, c = seg & 1;
        const int m = m_base + row, b = m >> 10, t = m & 1023;
        const float* xr = x + ((size_t)(b * 2 + c) * T_DIM + t) * F_DIM;
        const int fl = lo + 4 * q;
        float v0, v1, v2, v3;
        if (fl >= 0 && fl + 4 <= F_DIM) {
            const f4u vv = *reinterpret_cast<const f4u*>(xr + fl);
            v0 = vv.v[0]; v1 = vv.v[1]; v2 = vv.v[2]; v3 = vv.v[3];
        } else {
            const int e0 = min(max(fl, 0),     F_DIM - 1);
            const int e1 = min(max(fl + 1, 0), F_DIM - 1);
            const int e2 = min(max(fl + 2, 0), F_DIM - 1);
            const int e3 = min(max(fl + 3, 0), F_DIM - 1);
            v0 = xr[e0]; v1 = xr[e1]; v2 = xr[e2]; v3 = xr[e3];
        }
        const unsigned w0 = (unsigned)f2bf(v0) | ((unsigned)f2bf(v1) << 16);
        const unsigned w1 = (unsigned)f2bf(v2) | ((unsigned)f2bf(v3) << 16);
        unsigned* d = (unsigned*)&s_x[row][c * WIN + 4 * q];
        d[0] = w0; d[1] = w1;
    }
    __syncthreads();

    const int lane = tid & 63, wave = tid >> 6;   // wave in [0,8) = ct
    const int col  = lane & 15, kg  = lane >> 4;

    f32x4 acc[2];
#pragma unroll
    for (int mf = 0; mf < 2; ++mf) acc[mf] = (f32x4){0.f, 0.f, 0.f, 0.f};

    const bf16x8* bp = (const bf16x8*)(Mb + (size_t)chunk * KT2 * NCT * 512);

    bf16x8 b0, b1, b2, b3;
    b0 = bp[(size_t)(0 * NCT + wave) * 64 + lane];
    b1 = bp[(size_t)(1 * NCT + wave) * 64 + lane];
    b2 = bp[(size_t)(2 * NCT + wave) * 64 + lane];
    b3 = bp[(size_t)(3 * NCT + wave) * 64 + lane];

    bf16x8 aC0 = *(const bf16x8*)&s_x[col][kg * 8];
    bf16x8 aC1 = *(const bf16x8*)&s_x[16 + col][kg * 8];
    bf16x8 aN0, aN1;

#define PH(KT, BUF)                                                            \
    {                                                                          \
        if ((KT) + 1 < KT2) {                                                  \
            aN0 = *(const bf16x8*)&s_x[col][((KT) + 1) * 32 + kg * 8];         \
            aN1 = *(const bf16x8*)&s_x[16 + col][((KT) + 1) * 32 + kg * 8];    \
        }                                                                      \
        acc[0] = __builtin_amdgcn_mfma_f32_16x16x32_bf16(                      \
            aC0, BUF, acc[0], 0, 0, 0);                                        \
        acc[1] = __builtin_amdgcn_mfma_f32_16x16x32_bf16(                      \
            aC1, BUF, acc[1], 0, 0, 0);                                        \
        if ((KT) + 4 < KT2) {                                                  \
            BUF = bp[(size_t)(((KT) + 4) * NCT + wave) * 64 + lane];           \
        }                                                                      \
        aC0 = aN0; aC1 = aN1;                                                  \
    }

    PH(0, b0)  PH(1, b1)  PH(2, b2)  PH(3, b3)
    PH(4, b0)  PH(5, b1)  PH(6, b2)  PH(7, b3)
    PH(8, b0)  PH(9, b1)  PH(10, b2) PH(11, b3)
    PH(12, b0) PH(13, b1) PH(14, b2) PH(15, b3)
    PH(16, b0) PH(17, b1)
#undef PH

    // epilogue: dense store + bias
    const int b  = m_base >> 10;
    const int t0 = m_base & 1023;
    {
        const int i  = wave * 16 + col;       // [0, 128)
        const int c  = i >> 6, df = i & 63;
        const int f  = chunk * CHUNK + df;
        if (f < F_DIM) {
            const float bv = bias_g[c * F_DIM + f];
            float* orow = out + ((size_t)(b * 2 + c) * T_DIM + t0) * F_DIM + f;
#pragma unroll
            for (int mf = 0; mf < 2; ++mf)
#pragma unroll
                for (int reg = 0; reg < 4; ++reg) {
                    const int r = mf * 16 + kg * 4 + reg;
                    orow[(size_t)r * F_DIM] = acc[mf][reg] + bv;
                }
        }
    }
}

extern "C" void kernel_launch(void* const* d_in, const int* in_sizes, int n_in,
                              void* d_out, int out_size, void* d_ws, size_t ws_size,
                              hipStream_t stream) {
    const float* x      = (const float*)d_in[0];
    const float* pre_w  = (const float*)d_in[1];
    const float* pre_b  = (const float*)d_in[2];
    const float* post_w = (const float*)d_in[3];
    const float* post_b = (const float*)d_in[4];
    const int*   idx    = (const int*)d_in[5];
    const float* melw   = (const float*)d_in[6];
    const float* mask   = (const float*)d_in[7];
    const float* ola    = (const float*)d_in[8];
    float* out = (float*)d_out;

    const int W   = in_sizes[5] / K_BANDS;   // <= 112
    const int din = 2 * W;

    // workspace: Mf (banded f32) | bias | postP | Mb
    const size_t mf_bytes   = (size_t)NCHUNK * K2 * OC * 4;          // 5,013,504
    const size_t bias_bytes = 8448;
    float*          Mf     = (float*)d_ws;
    float*          bias_g = (float*)((char*)d_ws + mf_bytes);
    unsigned short* postP  = (unsigned short*)((char*)d_ws + mf_bytes + bias_bytes);
    const size_t frag_bytes = (size_t)K_BANDS * NKTC * NMT * 64 * 8 * 2; // 3,670,016
    unsigned short* Mb     = (unsigned short*)((char*)postP + frag_bytes);

    const int zcount = (int)((mf_bytes + bias_bytes) / 4);

    bs_prep<<<dim3(K_BANDS, NKTC), 256, 0, stream>>>(
        post_w, idx, melw, mask, ola, postP, (float*)d_ws, zcount, W, din);
    bs_compose<<<dim3(K_BANDS, NMT + 1), 256, 0, stream>>>(
        postP, pre_w, pre_b, post_w, post_b, idx, melw, mask, ola,
        Mf, bias_g, W, din);
    bs_mk_bf16<<<dim3(NCHUNK, KT2), 256, 0, stream>>>(Mf, Mb);

    bs_banded<<<dim3((B_DIM * T_DIM) / M_TILE, NCHUNK), 512, 0, stream>>>(
        x, Mb, bias_g, out);
}

// Round 18
// 69.173 us; speedup vs baseline: 1.1711x; 1.1711x over previous
//
#include <hip/hip_runtime.h>

// BandSplit R18: CHUNK back to 128 (R17's 64 regressed: staging redundancy).
// New bs_cvt pre-converts x to padded bf16 x_bf[(b,c,t)][1032] (+ absorbs
// Mf/bias zeroing); bs_banded stages via aligned ushort8 copies (no f2bf,
// no clamps off-edge) -- isolates staging cost as the last in-structure lever.

#define K_BANDS 64
#define COUT_D  128
#define T_DIM   1024
#define B_DIM   4
#define F_DIM   1025
#define XP      1032     // padded bf16 x row length (x8 -> 16B-aligned rows)
#define WPAD    112      // padded band width (W <= 112, verified R2-R17)
#define DINP    224      // 2*WPAD, channel-blocked j/i = c*112 + wi
#define NMT     14       // DINP/16 tiles (compose geometry)
#define NKTC    4        // 128/32 compose-K tiles
#define CHUNK   128      // output f-bins per chunk
#define NCHUNK  9        // ceil(1025/128)
#define WIN     352      // 112 + 128 + 112 input window
#define K2      704      // 2*WIN
#define KT2     22       // K2/32
#define OC      256      // out cols per chunk (2ch x 128)
#define NCT     16       // OC/16
#define M_TILE  32       // rows per main block
#define SXLD    712      // s_x row stride (shorts): 356 dw %32=4 -> spread

typedef __attribute__((ext_vector_type(8))) short bf16x8;
typedef __attribute__((ext_vector_type(4))) float f32x4;

__device__ __forceinline__ unsigned short f2bf(float f) {
    unsigned u = __builtin_bit_cast(unsigned, f);
    u += 0x7FFFu + ((u >> 16) & 1u);          // RNE
    return (unsigned short)(u >> 16);
}
__device__ __forceinline__ void st8(unsigned short* o, const unsigned short* v) {
    *(ushort4*)(o)     = make_ushort4(v[0], v[1], v[2], v[3]);
    *(ushort4*)(o + 4) = make_ushort4(v[4], v[5], v[6], v[7]);
}

struct alignas(4) f4u { float v[4]; };        // dword-aligned 16B load

// ---- cvt: x f32 -> padded bf16 x_bf rows of XP; also zero Mf+bias.
// grid = 8192 blocks (one x row each), 256 threads.
__global__ __launch_bounds__(256) void bs_cvt(
    const float* __restrict__ x, unsigned short* __restrict__ x_bf,
    float* __restrict__ zbase, int zcount)
{
    const int row = blockIdx.x;               // (b*2+c)*1024 + t
    const int tid = threadIdx.x;
    {
        const int i = blockIdx.x * 256 + tid;
        if (i < zcount) zbase[i] = 0.f;
    }
    const float* src = x + (size_t)row * F_DIM;
    unsigned short* dst = x_bf + (size_t)row * XP;
    for (int p = tid; p < XP / 4; p += 256) { // 258 4-elem chunks
        const int f = 4 * p;
        unsigned short v[4];
        if (f + 4 <= F_DIM) {
            const f4u vv = *reinterpret_cast<const f4u*>(src + f);
#pragma unroll
            for (int e = 0; e < 4; ++e) v[e] = f2bf(vv.v[e]);
        } else {
#pragma unroll
            for (int e = 0; e < 4; ++e)
                v[e] = (f + e < F_DIM) ? f2bf(src[f + e]) : (unsigned short)0;
        }
        *(ushort4*)(dst + f) = make_ushort4(v[0], v[1], v[2], v[3]);
    }
}

// ---- prep: pack post' B-frags (k, kt over o, ct over i, lane, 8), * sc(i)
__global__ __launch_bounds__(256) void bs_prep(
    const float* __restrict__ post_w, const int* __restrict__ idx,
    const float* __restrict__ melw, const float* __restrict__ mask,
    const float* __restrict__ ola, unsigned short* __restrict__ dstB,
    int W, int din)
{
    const int k = blockIdx.x, kt = blockIdx.y;
    for (int q = threadIdx.x; q < NMT * 64; q += 256) {
        const int ct = q >> 6, lane = q & 63;
        const int col = lane & 15, kg = lane >> 4;
        const int i  = ct * 16 + col;
        const int cc = (i >= WPAD);
        const int wi = i - cc * WPAD;
        float sc = 0.f;
        if (wi < W) {
            const float mw = melw[k * W + wi] * mask[k * W + wi];
            if (mw != 0.f) sc = 1.0f / ola[idx[k * W + wi]];
        }
        unsigned short v[8];
#pragma unroll
        for (int e = 0; e < 8; ++e) {
            const int o = kt * 32 + kg * 8 + e;
            const float f = (sc != 0.f)
                ? sc * post_w[((size_t)k * COUT_D + o) * din + 2 * wi + cc] : 0.f;
            v[e] = f2bf(f);
        }
        st8(dstB + ((((size_t)k * NKTC + kt) * NMT + ct) * 64 + lane) * 8, v);
    }
}

// ---- compose A_k = pre'^T x post', atomicAdd into banded Mf.
// A-frags built on the fly.  mt in [0,14): compose; mt == 14: bias.
__global__ __launch_bounds__(256) void bs_compose(
    const unsigned short* __restrict__ postP,
    const float* __restrict__ pre_w,  const float* __restrict__ pre_b,
    const float* __restrict__ post_w, const float* __restrict__ post_b,
    const int* __restrict__ idx, const float* __restrict__ melw,
    const float* __restrict__ mask, const float* __restrict__ ola,
    float* __restrict__ Mf, float* __restrict__ bias_g, int W, int din)
{
    __shared__ unsigned char s_flag[DINP];
    const int k   = blockIdx.x;
    const int mt  = blockIdx.y;
    const int tid = threadIdx.x;
    const int f0  = idx[(size_t)k * W];

    if (mt == NMT) {          // bias block
        if (tid >= DINP) return;
        const int c = tid >= WPAD, wi = tid - c * WPAD;
        if (wi >= W) return;
        if (melw[k * W + wi] * mask[k * W + wi] == 0.f) return;
        const int f = idx[k * W + wi];
        float v = post_b[(size_t)k * din + 2 * wi + c];
        for (int o = 0; o < COUT_D; ++o)
            v += pre_b[k * COUT_D + o]
                 * post_w[((size_t)k * COUT_D + o) * din + 2 * wi + c];
        atomicAdd(bias_g + c * F_DIM + f, v / ola[f]);
        return;
    }

    if (tid < DINP) {
        const int cc = tid >= WPAD, wi = tid - cc * WPAD;
        s_flag[tid] = (wi < W) && (melw[k * W + wi] * mask[k * W + wi] != 0.f);
    }
    __syncthreads();

    const int lane = tid & 63, wave = tid >> 6;
    const int col  = lane & 15, kg  = lane >> 4;
    const bf16x8* bp = (const bf16x8*)(postP + (size_t)k * NKTC * NMT * 512);

    bf16x8 a[NKTC];
    {
        const int jl  = mt * 16 + col;
        const int cc2 = jl >= WPAD, wj = jl - cc2 * WPAD;
        float wt = 0.f;
        if (wj < W) wt = melw[k * W + wj] * mask[k * W + wj];
#pragma unroll
        for (int kt = 0; kt < NKTC; ++kt) {
            bf16x8 av = (bf16x8){0, 0, 0, 0, 0, 0, 0, 0};
            if (wt != 0.f) {
                const float* src = pre_w
                    + ((size_t)k * din + 2 * wj + cc2) * COUT_D + kt * 32 + kg * 8;
                const f4u p0 = *(const f4u*)(src);
                const f4u p1 = *(const f4u*)(src + 4);
#pragma unroll
                for (int e = 0; e < 4; ++e) {
                    av[e]     = (short)f2bf(wt * p0.v[e]);
                    av[e + 4] = (short)f2bf(wt * p1.v[e]);
                }
            }
            a[kt] = av;
        }
    }

    for (int nt = wave; nt < NMT; nt += 4) {
        f32x4 acc = (f32x4){0.f, 0.f, 0.f, 0.f};
#pragma unroll
        for (int kt = 0; kt < NKTC; ++kt)
            acc = __builtin_amdgcn_mfma_f32_16x16x32_bf16(
                a[kt], bp[(kt * NMT + nt) * 64 + lane], acc, 0, 0, 0);
        const int i_loc = nt * 16 + col;
        if (!s_flag[i_loc]) continue;
        const int c  = i_loc >= WPAD, wi = i_loc - c * WPAD;
        const int f  = f0 + wi;
        const int ch = f >> 7, df = f & 127;   // CHUNK = 128
        const int lo = (ch << 7) - WPAD;
        const size_t colIdx = (size_t)(c * CHUNK + df);
#pragma unroll
        for (int reg = 0; reg < 4; ++reg) {
            const int j_loc = mt * 16 + kg * 4 + reg;
            if (!s_flag[j_loc]) continue;
            const int c2 = j_loc >= WPAD, wi2 = j_loc - c2 * WPAD;
            const int jj = f0 + wi2 - lo;      // in [1, 350]
            atomicAdd(Mf + ((size_t)ch * K2 + c2 * WIN + jj) * OC + colIdx,
                      acc[reg]);
        }
    }
}

// ---- convert banded Mf32 -> bf16 B-frags: (chunk, kt, ct, lane, 8)
__global__ __launch_bounds__(256) void bs_mk_bf16(
    const float* __restrict__ Mf, unsigned short* __restrict__ Mb)
{
    const int chunk = blockIdx.x, kt = blockIdx.y;
    for (int q = threadIdx.x; q < NCT * 64; q += 256) {
        const int ct = q >> 6, lane = q & 63;
        const int col = lane & 15, kg = lane >> 4;
        unsigned short v[8];
#pragma unroll
        for (int e = 0; e < 8; ++e) {
            const int jp = kt * 32 + kg * 8 + e;
            v[e] = f2bf(Mf[((size_t)chunk * K2 + jp) * OC + ct * 16 + col]);
        }
        st8(Mb + ((((size_t)chunk * KT2 + kt) * NCT + ct) * 64 + lane) * 8, v);
    }
}

// ---- main: out_row = M . x_window + bias. Staging = aligned ushort8 copies
// from pre-converted x_bf (no f2bf, clamps only at edge chunks).
__global__ __launch_bounds__(1024) void bs_banded(
    const unsigned short* __restrict__ x_bf,
    const unsigned short* __restrict__ Mb,
    const float* __restrict__ bias_g, float* __restrict__ out)
{
    __shared__ unsigned short s_x[M_TILE][SXLD];

    const int chunk  = blockIdx.y;                // t-tile fastest
    const int m_base = blockIdx.x * M_TILE;
    const int tid    = threadIdx.x;
    const int lo     = chunk * CHUNK - WPAD;      // f-space window start

    // stage: 32 rows x 2 ch x 44 ushort8 chunks
    for (int p = tid; p < M_TILE * 2 * 44; p += 1024) {
        const int seg = p / 44, q = p - seg * 44;
        const int row = seg >> 1, c = seg & 1;
        const int m = m_base + row, b = m >> 10, t = m & 1023;
        const unsigned short* sr = x_bf + ((size_t)(b * 2 + c) * T_DIM + t) * XP;
        const int fl = lo + 8 * q;
        bf16x8 v;
        if (fl >= 0 && fl + 8 <= XP) {
            v = *(const bf16x8*)(sr + fl);        // 16B-aligned fast path
        } else {                                  // edge chunks: clamp addr
#pragma unroll
            for (int e = 0; e < 8; ++e) {
                const int f = min(max(fl + e, 0), F_DIM - 1);
                v[e] = (short)sr[f];
            }
        }
        *(bf16x8*)&s_x[row][c * WIN + 8 * q] = v;
    }
    __syncthreads();

    const int lane = tid & 63, wave = tid >> 6;   // wave in [0,16) = ct
    const int col  = lane & 15, kg  = lane >> 4;

    f32x4 acc[2];
#pragma unroll
    for (int mf = 0; mf < 2; ++mf) acc[mf] = (f32x4){0.f, 0.f, 0.f, 0.f};

    const bf16x8* bp = (const bf16x8*)(Mb + (size_t)chunk * KT2 * NCT * 512);

    bf16x8 b0, b1, b2, b3;
    b0 = bp[(size_t)(0 * NCT + wave) * 64 + lane];
    b1 = bp[(size_t)(1 * NCT + wave) * 64 + lane];
    b2 = bp[(size_t)(2 * NCT + wave) * 64 + lane];
    b3 = bp[(size_t)(3 * NCT + wave) * 64 + lane];

    bf16x8 aC0 = *(const bf16x8*)&s_x[col][kg * 8];
    bf16x8 aC1 = *(const bf16x8*)&s_x[16 + col][kg * 8];
    bf16x8 aN0, aN1;

#define PH(KT, BUF)                                                            \
    {                                                                          \
        if ((KT) + 1 < KT2) {                                                  \
            aN0 = *(const bf16x8*)&s_x[col][((KT) + 1) * 32 + kg * 8];         \
            aN1 = *(const bf16x8*)&s_x[16 + col][((KT) + 1) * 32 + kg * 8];    \
        }                                                                      \
        acc[0] = __builtin_amdgcn_mfma_f32_16x16x32_bf16(                      \
            aC0, BUF, acc[0], 0, 0, 0);                                        \
        acc[1] = __builtin_amdgcn_mfma_f32_16x16x32_bf16(                      \
            aC1, BUF, acc[1], 0, 0, 0);                                        \
        if ((KT) + 4 < KT2) {                                                  \
            BUF = bp[(size_t)(((KT) + 4) * NCT + wave) * 64 + lane];           \
        }                                                                      \
        aC0 = aN0; aC1 = aN1;                                                  \
    }

    PH(0, b0)  PH(1, b1)  PH(2, b2)  PH(3, b3)
    PH(4, b0)  PH(5, b1)  PH(6, b2)  PH(7, b3)
    PH(8, b0)  PH(9, b1)  PH(10, b2) PH(11, b3)
    PH(12, b0) PH(13, b1) PH(14, b2) PH(15, b3)
    PH(16, b0) PH(17, b1) PH(18, b2) PH(19, b3)
    PH(20, b0) PH(21, b1)
#undef PH

    // epilogue: dense store + bias
    const int b  = m_base >> 10;
    const int t0 = m_base & 1023;
    {
        const int i  = wave * 16 + col;
        const int c  = i >> 7, df = i & 127;
        const int f  = chunk * CHUNK + df;
        if (f < F_DIM) {
            const float bv = bias_g[c * F_DIM + f];
            float* orow = out + ((size_t)(b * 2 + c) * T_DIM + t0) * F_DIM + f;
#pragma unroll
            for (int mf = 0; mf < 2; ++mf)
#pragma unroll
                for (int reg = 0; reg < 4; ++reg) {
                    const int r = mf * 16 + kg * 4 + reg;
                    orow[(size_t)r * F_DIM] = acc[mf][reg] + bv;
                }
        }
    }
}

extern "C" void kernel_launch(void* const* d_in, const int* in_sizes, int n_in,
                              void* d_out, int out_size, void* d_ws, size_t ws_size,
                              hipStream_t stream) {
    const float* x      = (const float*)d_in[0];
    const float* pre_w  = (const float*)d_in[1];
    const float* pre_b  = (const float*)d_in[2];
    const float* post_w = (const float*)d_in[3];
    const float* post_b = (const float*)d_in[4];
    const int*   idx    = (const int*)d_in[5];
    const float* melw   = (const float*)d_in[6];
    const float* mask   = (const float*)d_in[7];
    const float* ola    = (const float*)d_in[8];
    float* out = (float*)d_out;

    const int W   = in_sizes[5] / K_BANDS;   // <= 112
    const int din = 2 * W;

    // workspace: Mf | bias | postP | Mb | x_bf   (~30.3 MB)
    const size_t mf_bytes   = (size_t)NCHUNK * K2 * OC * 4;          // 6,488,064
    const size_t bias_bytes = 8448;
    float*          Mf     = (float*)d_ws;
    float*          bias_g = (float*)((char*)d_ws + mf_bytes);
    unsigned short* postP  = (unsigned short*)((char*)d_ws + mf_bytes + bias_bytes);
    const size_t frag_bytes = (size_t)K_BANDS * NKTC * NMT * 64 * 8 * 2; // 3,670,016
    unsigned short* Mb     = (unsigned short*)((char*)postP + frag_bytes);
    const size_t mb_bytes   = (size_t)NCHUNK * KT2 * NCT * 64 * 8 * 2;   // 3,244,032
    unsigned short* x_bf   = (unsigned short*)((char*)Mb + mb_bytes);

    const int zcount = (int)((mf_bytes + bias_bytes) / 4);

    bs_cvt<<<B_DIM * 2 * T_DIM, 256, 0, stream>>>(x, x_bf, (float*)d_ws, zcount);
    bs_prep<<<dim3(K_BANDS, NKTC), 256, 0, stream>>>(
        post_w, idx, melw, mask, ola, postP, W, din);
    bs_compose<<<dim3(K_BANDS, NMT + 1), 256, 0, stream>>>(
        postP, pre_w, pre_b, post_w, post_b, idx, melw, mask, ola,
        Mf, bias_g, W, din);
    bs_mk_bf16<<<dim3(NCHUNK, KT2), 256, 0, stream>>>(Mf, Mb);

    bs_banded<<<dim3((B_DIM * T_DIM) / M_TILE, NCHUNK), 1024, 0, stream>>>(
        x_bf, Mb, bias_g, out);
}